// Round 16
// baseline (1271.906 us; speedup 1.0000x reference)
//
#include <hip/hip_runtime.h>
#include <hip/hip_bf16.h>

#define NN 50000
#define EE 800000
#define HH 128

typedef __attribute__((ext_vector_type(8))) short bf16x8;
typedef __attribute__((ext_vector_type(4))) float f32x4;

__device__ inline unsigned short f2bf(float f) {
    union { float f; unsigned u; } v; v.f = f;
    unsigned r = v.u + 0x7FFF + ((v.u >> 16) & 1);
    return (unsigned short)(r >> 16);
}
__device__ inline float bf2f(unsigned short u) {
    union { unsigned u32; float f; } v; v.u32 = (unsigned)u << 16; return v.f;
}

// LDS-only barrier (lgkmcnt drain + raw s_barrier; no vmcnt drain).
__device__ __forceinline__ void lds_barrier() {
    asm volatile("s_waitcnt lgkmcnt(0)" ::: "memory");
    __builtin_amdgcn_sched_barrier(0);
    __builtin_amdgcn_s_barrier();
}

// ---------------- CSR build (edges grouped by dst) ----------------
__global__ __launch_bounds__(256) void hist_k(const int* __restrict__ dst, int* __restrict__ cnt) {
    int i = blockIdx.x * 256 + threadIdx.x;
    if (i < EE) atomicAdd(&cnt[dst[i]], 1);
}

__global__ __launch_bounds__(256) void blocksum_k(const int* __restrict__ cnt, int* __restrict__ bsum) {
    __shared__ int sm[256];
    int i = blockIdx.x * 256 + threadIdx.x;
    sm[threadIdx.x] = (i < NN) ? cnt[i] : 0;
    __syncthreads();
    for (int s = 128; s > 0; s >>= 1) {
        if (threadIdx.x < s) sm[threadIdx.x] += sm[threadIdx.x + s];
        __syncthreads();
    }
    if (threadIdx.x == 0) bsum[blockIdx.x] = sm[0];
}

__global__ __launch_bounds__(256) void scanb_k(int* __restrict__ bsum, int nb) {
    __shared__ int sm[256];
    int t = threadIdx.x;
    sm[t] = (t < nb) ? bsum[t] : 0;
    __syncthreads();
    for (int d = 1; d < 256; d <<= 1) {
        int v = (t >= d) ? sm[t - d] : 0;
        __syncthreads();
        sm[t] += v;
        __syncthreads();
    }
    if (t < nb) bsum[t] = sm[t];
}

__global__ __launch_bounds__(256) void offsets_k(const int* __restrict__ cnt, const int* __restrict__ bsum,
                                                 int* __restrict__ offsets, int* __restrict__ cursor) {
    __shared__ int sm[256];
    int b = blockIdx.x, t = threadIdx.x;
    int i = b * 256 + t;
    int c = (i < NN) ? cnt[i] : 0;
    sm[t] = c;
    __syncthreads();
    for (int d = 1; d < 256; d <<= 1) {
        int v = (t >= d) ? sm[t - d] : 0;
        __syncthreads();
        sm[t] += v;
        __syncthreads();
    }
    int incl = sm[t];
    int base = (b == 0) ? 0 : bsum[b - 1];
    int off = base + incl - c;
    if (i < NN) { offsets[i] = off; cursor[i] = off; }
    if (i == NN - 1) offsets[NN] = off + c;
}

// fill CSR edge list; also materialize CSR-ordered src/dst
__global__ __launch_bounds__(256) void fill_k(const int* __restrict__ src, const int* __restrict__ dst,
                                              int* __restrict__ cursor, int* __restrict__ eids,
                                              int* __restrict__ srcc, int* __restrict__ dstc) {
    int i = blockIdx.x * 256 + threadIdx.x;
    if (i < EE) {
        int d = dst[i];
        int p = atomicAdd(&cursor[d], 1);
        eids[p] = i;
        srcc[p] = src[i];
        dstc[p] = d;
    }
}

// ---------------- weight prep: W[fi][fo] f32 -> W_t[n][k] bf16 (plain transpose) ----------------
__global__ __launch_bounds__(256) void wprep_k(const float* __restrict__ W, unsigned short* __restrict__ out,
                                               int fi, int fo, int n_off, int out_ld) {
    int i = blockIdx.x * 256 + threadIdx.x;
    if (i >= fi * fo) return;
    int n = i / fi, k = i - n * fi;
    out[(size_t)(n_off + n) * out_ld + k] = f2bf(W[(size_t)k * fo + n]);
}

// ---------------- f32 -> bf16 bulk convert (8 elems/thread) ----------------
__global__ __launch_bounds__(256) void cvt_k(const float* __restrict__ in, unsigned short* __restrict__ out,
                                             long n8) {
    long i = (long)blockIdx.x * 256 + threadIdx.x;
    if (i >= n8) return;
    const float4* p = (const float4*)in + i * 2;
    float4 a = p[0], b = p[1];
    bf16x8 o = {(short)f2bf(a.x), (short)f2bf(a.y), (short)f2bf(a.z), (short)f2bf(a.w),
                (short)f2bf(b.x), (short)f2bf(b.y), (short)f2bf(b.z), (short)f2bf(b.w)};
    *((bf16x8*)out + i) = o;
}

// ---------------- CSR-ordered bf16 copy of e ----------------
__global__ __launch_bounds__(256) void cvtcsr_k(const float* __restrict__ e, const int* __restrict__ eids,
                                                unsigned short* __restrict__ out) {
    long gid = (long)blockIdx.x * 256 + threadIdx.x;
    long j = gid >> 4;
    if (j >= EE) return;
    int part = (int)(gid & 15);
    int rid = eids[j];
    const float4* p = (const float4*)(e + (size_t)rid * HH + part * 8);
    float4 a = p[0], b = p[1];
    bf16x8 o = {(short)f2bf(a.x), (short)f2bf(a.y), (short)f2bf(a.z), (short)f2bf(a.w),
                (short)f2bf(b.x), (short)f2bf(b.y), (short)f2bf(b.z), (short)f2bf(b.w)};
    *((bf16x8*)(out + (size_t)j * HH + part * 8)) = o;
}

// ---------------- single-barrier MFMA gather-GEMM (used for Q) ----------------
template <int G, int NCW, int RT, int MODE>
__global__ __launch_bounds__(512, 2) void mm4_k(
    const unsigned short* __restrict__ A0, const int* __restrict__ idx0,
    const unsigned short* __restrict__ Wt, const float* __restrict__ bias,
    int M,
    float* __restrict__ Cf, unsigned short* __restrict__ Cb, int out_ld)
{
    constexpr int RW = 8 / NCW;
    constexpr int ROWS = RW * RT * 16;
    constexpr int Ktot = G * 128;
    constexpr int SI = ROWS / 32;
    __shared__ unsigned short Asl[G * ROWS * 128];

    const int t = threadIdx.x;
    const int wid = t >> 6, lane = t & 63;
    const int lr = lane & 15, lk = lane >> 4;
    const int colw = wid & 3;
    const int roww = wid >> 2;
    const int col0 = colw << 5;
    const int tbase = blockIdx.x * ROWS;

    #pragma unroll
    for (int g = 0; g < G; ++g) {
        #pragma unroll
        for (int i = 0; i < SI; ++i) {
            int rl = ((i * 8 + wid) << 2) + (lane >> 4);
            int gr = tbase + rl; if (gr >= M) gr = M - 1;
            int rid = idx0 ? idx0[gr] : gr;
            const unsigned short* src = A0 + (size_t)rid * HH + (((lane & 15) ^ (rl & 7)) << 3);
            unsigned short* dst = &Asl[(g * ROWS + ((i * 8 + wid) << 2)) << 7];
            __builtin_amdgcn_global_load_lds((const __attribute__((address_space(1))) void*)src,
                                             (__attribute__((address_space(3))) void*)dst, 16, 0, 0);
        }
    }

    f32x4 acc[RT][2];
    #pragma unroll
    for (int tt = 0; tt < RT; ++tt) { acc[tt][0] = (f32x4){0,0,0,0}; acc[tt][1] = (f32x4){0,0,0,0}; }

    __syncthreads();

    #pragma unroll
    for (int g = 0; g < G; ++g) {
        bf16x8 b[4][2];
        #pragma unroll
        for (int s = 0; s < 4; ++s)
            #pragma unroll
            for (int c = 0; c < 2; ++c)
                b[s][c] = *(const bf16x8*)(Wt + (size_t)(col0 + (c << 4) + lr) * Ktot + (g << 7) + (s << 5) + (lk << 3));

        #pragma unroll
        for (int tt = 0; tt < RT; ++tt) {
            const int tl = (tt * RW + roww) << 4;
            bf16x8 a[4];
            #pragma unroll
            for (int s = 0; s < 4; ++s) {
                const int c16 = ((s << 2) + lk) ^ (lr & 7);
                a[s] = *(const bf16x8*)&Asl[((g * ROWS + tl + lr) << 7) + (c16 << 3)];
            }
            #pragma unroll
            for (int s = 0; s < 4; ++s) {
                acc[tt][0] = __builtin_amdgcn_mfma_f32_16x16x32_bf16(a[s], b[s][0], acc[tt][0], 0, 0, 0);
                acc[tt][1] = __builtin_amdgcn_mfma_f32_16x16x32_bf16(a[s], b[s][1], acc[tt][1], 0, 0, 0);
            }
        }
    }

    float bias2[2] = {bias[col0 + lr], bias[col0 + 16 + lr]};
    #pragma unroll
    for (int tt = 0; tt < RT; ++tt) {
        #pragma unroll
        for (int rr = 0; rr < 4; ++rr) {
            int row = tbase + ((tt * RW + roww) << 4) + (lk << 2) + rr;
            if (row >= M) continue;
            #pragma unroll
            for (int c = 0; c < 2; ++c) {
                float v = acc[tt][c][rr] + bias2[c];
                if (MODE == 1) v = fmaxf(v, 0.f);
                size_t o = (size_t)row * out_ld + col0 + (c << 4) + lr;
                if (MODE == 0 || MODE == 1) Cf[o] = v;
                else Cb[o] = f2bf(v);
            }
        }
    }
}

// ---------------- fused 2-layer MLP + resid + LN (node version) ----------------
template <int G, int RT>
__global__ __launch_bounds__(512, 2) void mlp_k(
    const unsigned short* __restrict__ A0, const int* __restrict__ idx0,
    const unsigned short* __restrict__ W1t, const float* __restrict__ b1,
    const unsigned short* __restrict__ W2t, const float* __restrict__ b2,
    int M,
    float* __restrict__ Cf, unsigned short* __restrict__ Cb2,
    const float* __restrict__ resid, const float* __restrict__ gamma, const float* __restrict__ beta)
{
    constexpr int RW = 2, NCW = 4;
    constexpr int ROWS = RW * RT * 16;
    constexpr int K1 = G * 128;
    constexpr int SI = ROWS / 32;
    __shared__ unsigned short Asl[G * ROWS * 128];   // first ROWS*128 shorts reused as t-buffer
    __shared__ float lnbuf[RT * 32 * 8];

    const int t = threadIdx.x;
    const int wid = t >> 6, lane = t & 63;
    const int lr = lane & 15, lk = lane >> 4;
    const int colw = wid & 3, roww = wid >> 2;
    const int col0 = colw << 5;
    const int tbase = blockIdx.x * ROWS;

    #pragma unroll
    for (int g = 0; g < G; ++g) {
        #pragma unroll
        for (int i = 0; i < SI; ++i) {
            int rl = ((i * 8 + wid) << 2) + (lane >> 4);
            int gr = tbase + rl; if (gr >= M) gr = M - 1;
            int rid = idx0 ? idx0[gr] : gr;
            const unsigned short* src = A0 + (size_t)rid * HH + (((lane & 15) ^ (rl & 7)) << 3);
            unsigned short* dst = &Asl[(g * ROWS + ((i * 8 + wid) << 2)) << 7];
            __builtin_amdgcn_global_load_lds((const __attribute__((address_space(1))) void*)src,
                                             (__attribute__((address_space(3))) void*)dst, 16, 0, 0);
        }
    }

    f32x4 acc[RT][2];
    #pragma unroll
    for (int tt = 0; tt < RT; ++tt) { acc[tt][0] = (f32x4){0,0,0,0}; acc[tt][1] = (f32x4){0,0,0,0}; }

    __syncthreads();

    #pragma unroll
    for (int g = 0; g < G; ++g) {
        bf16x8 b[4][2];
        #pragma unroll
        for (int s = 0; s < 4; ++s)
            #pragma unroll
            for (int c = 0; c < 2; ++c)
                b[s][c] = *(const bf16x8*)(W1t + (size_t)(col0 + (c << 4) + lr) * K1 + (g << 7) + (s << 5) + (lk << 3));

        #pragma unroll
        for (int tt = 0; tt < RT; ++tt) {
            const int tl = (tt * RW + roww) << 4;
            bf16x8 a[4];
            #pragma unroll
            for (int s = 0; s < 4; ++s) {
                const int c16 = ((s << 2) + lk) ^ (lr & 7);
                a[s] = *(const bf16x8*)&Asl[((g * ROWS + tl + lr) << 7) + (c16 << 3)];
            }
            #pragma unroll
            for (int s = 0; s < 4; ++s) {
                acc[tt][0] = __builtin_amdgcn_mfma_f32_16x16x32_bf16(a[s], b[s][0], acc[tt][0], 0, 0, 0);
                acc[tt][1] = __builtin_amdgcn_mfma_f32_16x16x32_bf16(a[s], b[s][1], acc[tt][1], 0, 0, 0);
            }
        }
    }

    __syncthreads();

    {
        float b1c[2] = {b1[col0 + lr], b1[col0 + 16 + lr]};
        #pragma unroll
        for (int tt = 0; tt < RT; ++tt) {
            #pragma unroll
            for (int rr = 0; rr < 4; ++rr) {
                int rowl = ((tt * RW + roww) << 4) + (lk << 2) + rr;
                #pragma unroll
                for (int c = 0; c < 2; ++c) {
                    int col = col0 + (c << 4) + lr;
                    int chunk = (col >> 3) ^ (rowl & 7);
                    Asl[(rowl << 7) + (chunk << 3) + (col & 7)] =
                        f2bf(fmaxf(acc[tt][c][rr] + b1c[c], 0.f));
                }
            }
        }
    }

    __syncthreads();

    f32x4 acc2[RT][2];
    #pragma unroll
    for (int tt = 0; tt < RT; ++tt) { acc2[tt][0] = (f32x4){0,0,0,0}; acc2[tt][1] = (f32x4){0,0,0,0}; }

    {
        bf16x8 b[4][2];
        #pragma unroll
        for (int s = 0; s < 4; ++s)
            #pragma unroll
            for (int c = 0; c < 2; ++c)
                b[s][c] = *(const bf16x8*)(W2t + (size_t)(col0 + (c << 4) + lr) * 128 + (s << 5) + (lk << 3));

        #pragma unroll
        for (int tt = 0; tt < RT; ++tt) {
            const int tl = (tt * RW + roww) << 4;
            bf16x8 a[4];
            #pragma unroll
            for (int s = 0; s < 4; ++s) {
                const int c16 = ((s << 2) + lk) ^ (lr & 7);
                a[s] = *(const bf16x8*)&Asl[((tl + lr) << 7) + (c16 << 3)];
            }
            #pragma unroll
            for (int s = 0; s < 4; ++s) {
                acc2[tt][0] = __builtin_amdgcn_mfma_f32_16x16x32_bf16(a[s], b[s][0], acc2[tt][0], 0, 0, 0);
                acc2[tt][1] = __builtin_amdgcn_mfma_f32_16x16x32_bf16(a[s], b[s][1], acc2[tt][1], 0, 0, 0);
            }
        }
    }

    float b2c[2] = {b2[col0 + lr], b2[col0 + 16 + lr]};
    float g2[2] = {gamma[col0 + lr], gamma[col0 + 16 + lr]};
    float be2[2] = {beta[col0 + lr], beta[col0 + 16 + lr]};

    #pragma unroll
    for (int tt = 0; tt < RT; ++tt) {
        #pragma unroll
        for (int rr = 0; rr < 4; ++rr) {
            int row = tbase + ((tt * RW + roww) << 4) + (lk << 2) + rr;
            int rowc = (row < M) ? row : M - 1;
            float sum = 0.f, sq = 0.f;
            #pragma unroll
            for (int c = 0; c < 2; ++c) {
                float v = fmaxf(acc2[tt][c][rr] + b2c[c], 0.f);
                v += resid[(size_t)rowc * HH + col0 + (c << 4) + lr];
                acc2[tt][c][rr] = v;
                sum += v; sq += v * v;
            }
            sum += __shfl_xor(sum, 1); sq += __shfl_xor(sq, 1);
            sum += __shfl_xor(sum, 2); sq += __shfl_xor(sq, 2);
            sum += __shfl_xor(sum, 4); sq += __shfl_xor(sq, 4);
            sum += __shfl_xor(sum, 8); sq += __shfl_xor(sq, 8);
            if (lr == 0) {
                int rls = (roww << 4) + (lk << 2) + rr;
                lnbuf[((tt * 32 + rls) << 3) + (colw << 1) + 0] = sum;
                lnbuf[((tt * 32 + rls) << 3) + (colw << 1) + 1] = sq;
            }
        }
    }
    __syncthreads();
    #pragma unroll
    for (int tt = 0; tt < RT; ++tt) {
        #pragma unroll
        for (int rr = 0; rr < 4; ++rr) {
            int rls = (roww << 4) + (lk << 2) + rr;
            float s4 = 0.f, q4 = 0.f;
            #pragma unroll
            for (int cw = 0; cw < 4; ++cw) {
                s4 += lnbuf[((tt * 32 + rls) << 3) + (cw << 1) + 0];
                q4 += lnbuf[((tt * 32 + rls) << 3) + (cw << 1) + 1];
            }
            const float mean = s4 * (1.f / 128.f);
            const float var = q4 * (1.f / 128.f) - mean * mean;
            const float rs = rsqrtf(var + 1e-5f);
            int row = tbase + ((tt * RW + roww) << 4) + (lk << 2) + rr;
            if (row < M) {
                #pragma unroll
                for (int c = 0; c < 2; ++c) {
                    float o = (acc2[tt][c][rr] - mean) * rs * g2[c] + be2[c];
                    size_t idx = (size_t)row * HH + col0 + (c << 4) + lr;
                    Cf[idx] = o;
                    if (Cb2) Cb2[idx] = f2bf(o);
                }
            }
        }
    }
}

// ---------------- EDGE MLP: e staged ONCE as f32; bf16 conversion DEDUPED ----------------
// Change vs R15: the e k-chunk's f32->bf16 conversion was done 4x redundantly (all
// col-waves converting the same 64x128 block per-fragment). Now: each thread reads
// its LN residuals + a 16-element conversion slice into regs -> lds_barrier ->
// cooperative IN-PLACE bf16 write into Esl's first half (Asl chunk-XOR layout) ->
// lds_barrier -> GEMM1 g==2 reads bf16 fragments like any other chunk (zero VALU),
// LN uses register residuals. Same f2bf rounding = bitwise identical output.
__global__ __launch_bounds__(512, 2) void mlpe_k(
    const unsigned short* __restrict__ ho, const int* __restrict__ src,
    const int* __restrict__ dst, const float* __restrict__ e,
    const unsigned short* __restrict__ W1t, const float* __restrict__ b1,
    const unsigned short* __restrict__ W2t, const float* __restrict__ b2,
    int M,
    float* __restrict__ Cf,
    const float* __restrict__ gamma, const float* __restrict__ beta)
{
    constexpr int RW = 2, RT = 2;
    constexpr int ROWS = RW * RT * 16;      // 64
    constexpr int K1 = 384;
    __shared__ unsigned short Asl[2 * ROWS * 128];  // chunks 0,1 (bf16); chunk0 reused as t-buffer
    __shared__ float Esl[ROWS * 128];               // e f32 (16B-chunk swizzled); first half reused as bf16
    __shared__ float lnbuf[RT * 32 * 8];

    const int t = threadIdx.x;
    const int wid = t >> 6, lane = t & 63;
    const int lr = lane & 15, lk = lane >> 4;
    const int colw = wid & 3, roww = wid >> 2;
    const int col0 = colw << 5;
    const int tbase = blockIdx.x * ROWS;

    unsigned short* EslBf = (unsigned short*)Esl;   // bf16 alias (first 16KB after conversion)

    // ---- stage bf16 chunks: ho[src], ho[dst] ----
    #pragma unroll
    for (int g = 0; g < 2; ++g) {
        const int* ig = g ? dst : src;
        #pragma unroll
        for (int i = 0; i < 2; ++i) {
            int rl = ((i * 8 + wid) << 2) + (lane >> 4);
            int gr = tbase + rl; if (gr >= M) gr = M - 1;
            int rid = ig[gr];
            const unsigned short* sp = ho + (size_t)rid * HH + (((lane & 15) ^ (rl & 7)) << 3);
            unsigned short* dp = &Asl[(g * ROWS + ((i * 8 + wid) << 2)) << 7];
            __builtin_amdgcn_global_load_lds((const __attribute__((address_space(1))) void*)sp,
                                             (__attribute__((address_space(3))) void*)dp, 16, 0, 0);
        }
    }
    // ---- stage e rows f32 (source 16B-chunk swizzled; LDS dest linear) ----
    #pragma unroll
    for (int i = 0; i < 4; ++i) {
        int row = i * 16 + wid * 2 + (lane >> 5);
        int c16 = lane & 31;
        int c16s = (c16 & 24) | ((c16 & 7) ^ (row & 7));
        int gr = tbase + row; if (gr >= M) gr = M - 1;
        const float* sp = e + (size_t)gr * HH + c16s * 4;
        float* dbase = Esl + (size_t)(i * 512 + wid * 64) * 4;
        __builtin_amdgcn_global_load_lds((const __attribute__((address_space(1))) void*)sp,
                                         (__attribute__((address_space(3))) void*)dbase, 16, 0, 0);
    }

    f32x4 acc[RT][2];
    #pragma unroll
    for (int tt = 0; tt < RT; ++tt) { acc[tt][0] = (f32x4){0,0,0,0}; acc[tt][1] = (f32x4){0,0,0,0}; }

    __syncthreads();

    // ---- Phase A (reads only): residuals + conversion slice into regs ----
    float rp[RT][4][2];
    #pragma unroll
    for (int tt = 0; tt < RT; ++tt) {
        #pragma unroll
        for (int rr = 0; rr < 4; ++rr) {
            int rowl = ((tt * RW + roww) << 4) + (lk << 2) + rr;
            #pragma unroll
            for (int c = 0; c < 2; ++c) {
                int col = col0 + (c << 4) + lr;
                int c16 = col >> 2;
                int cs = (c16 & 24) | ((c16 & 7) ^ (rowl & 7));
                rp[tt][rr][c] = Esl[rowl * 128 + cs * 4 + (col & 3)];
            }
        }
    }
    const int cr = t >> 3;            // conversion row 0..63 (8 threads/row)
    const int cc0 = (t & 7) * 16;     // 16 cols per thread
    float4 cf[4];
    #pragma unroll
    for (int j = 0; j < 4; ++j) {
        int c16 = (cc0 >> 2) + j;
        int cs = (c16 & 24) | ((c16 & 7) ^ (cr & 7));
        cf[j] = *(const float4*)&Esl[cr * 128 + cs * 4];
    }
    lds_barrier();                    // all f32 reads done before overwrite

    // ---- Phase B: write bf16 (chunk-XOR layout) into Esl's first half ----
    {
        int chA = ((cc0 >> 3) + 0) ^ (cr & 7);
        int chB = ((cc0 >> 3) + 1) ^ (cr & 7);
        bf16x8 oa = {(short)f2bf(cf[0].x), (short)f2bf(cf[0].y), (short)f2bf(cf[0].z), (short)f2bf(cf[0].w),
                     (short)f2bf(cf[1].x), (short)f2bf(cf[1].y), (short)f2bf(cf[1].z), (short)f2bf(cf[1].w)};
        bf16x8 ob = {(short)f2bf(cf[2].x), (short)f2bf(cf[2].y), (short)f2bf(cf[2].z), (short)f2bf(cf[2].w),
                     (short)f2bf(cf[3].x), (short)f2bf(cf[3].y), (short)f2bf(cf[3].z), (short)f2bf(cf[3].w)};
        *(bf16x8*)&EslBf[(cr << 7) + (chA << 3)] = oa;
        *(bf16x8*)&EslBf[(cr << 7) + (chB << 3)] = ob;
    }
    lds_barrier();                    // bf16 chunk visible

    // ---- GEMM1 over K=384: all three chunks now identical bf16 fragment reads ----
    #pragma unroll
    for (int g = 0; g < 3; ++g) {
        bf16x8 b[4][2];
        #pragma unroll
        for (int s = 0; s < 4; ++s)
            #pragma unroll
            for (int c = 0; c < 2; ++c)
                b[s][c] = *(const bf16x8*)(W1t + (size_t)(col0 + (c << 4) + lr) * K1 + (g << 7) + (s << 5) + (lk << 3));

        #pragma unroll
        for (int tt = 0; tt < RT; ++tt) {
            const int r = ((tt * RW + roww) << 4) + lr;
            bf16x8 a[4];
            #pragma unroll
            for (int s = 0; s < 4; ++s) {
                const int c16 = ((s << 2) + lk) ^ (lr & 7);
                a[s] = (g < 2) ? *(const bf16x8*)&Asl[((g * ROWS + r) << 7) + (c16 << 3)]
                               : *(const bf16x8*)&EslBf[(r << 7) + (c16 << 3)];
            }
            #pragma unroll
            for (int s = 0; s < 4; ++s) {
                acc[tt][0] = __builtin_amdgcn_mfma_f32_16x16x32_bf16(a[s], b[s][0], acc[tt][0], 0, 0, 0);
                acc[tt][1] = __builtin_amdgcn_mfma_f32_16x16x32_bf16(a[s], b[s][1], acc[tt][1], 0, 0, 0);
            }
        }
    }

    __syncthreads();   // all chunk-0 reads done; t-buffer may overwrite it

    // ---- t = relu(acc + b1) -> LDS bf16 (chunk-0 region, XOR-swizzled) ----
    {
        float b1c[2] = {b1[col0 + lr], b1[col0 + 16 + lr]};
        #pragma unroll
        for (int tt = 0; tt < RT; ++tt) {
            #pragma unroll
            for (int rr = 0; rr < 4; ++rr) {
                int rowl = ((tt * RW + roww) << 4) + (lk << 2) + rr;
                #pragma unroll
                for (int c = 0; c < 2; ++c) {
                    int col = col0 + (c << 4) + lr;
                    int chunk = (col >> 3) ^ (rowl & 7);
                    Asl[(rowl << 7) + (chunk << 3) + (col & 7)] =
                        f2bf(fmaxf(acc[tt][c][rr] + b1c[c], 0.f));
                }
            }
        }
    }

    __syncthreads();

    // ---- GEMM2: t @ W2 ----
    f32x4 acc2[RT][2];
    #pragma unroll
    for (int tt = 0; tt < RT; ++tt) { acc2[tt][0] = (f32x4){0,0,0,0}; acc2[tt][1] = (f32x4){0,0,0,0}; }

    {
        bf16x8 b[4][2];
        #pragma unroll
        for (int s = 0; s < 4; ++s)
            #pragma unroll
            for (int c = 0; c < 2; ++c)
                b[s][c] = *(const bf16x8*)(W2t + (size_t)(col0 + (c << 4) + lr) * 128 + (s << 5) + (lk << 3));

        #pragma unroll
        for (int tt = 0; tt < RT; ++tt) {
            const int tl = (tt * RW + roww) << 4;
            bf16x8 a[4];
            #pragma unroll
            for (int s = 0; s < 4; ++s) {
                const int c16 = ((s << 2) + lk) ^ (lr & 7);
                a[s] = *(const bf16x8*)&Asl[((tl + lr) << 7) + (c16 << 3)];
            }
            #pragma unroll
            for (int s = 0; s < 4; ++s) {
                acc2[tt][0] = __builtin_amdgcn_mfma_f32_16x16x32_bf16(a[s], b[s][0], acc2[tt][0], 0, 0, 0);
                acc2[tt][1] = __builtin_amdgcn_mfma_f32_16x16x32_bf16(a[s], b[s][1], acc2[tt][1], 0, 0, 0);
            }
        }
    }

    // ---- LN epilogue: residual from registers ----
    float b2c[2] = {b2[col0 + lr], b2[col0 + 16 + lr]};
    float g2[2] = {gamma[col0 + lr], gamma[col0 + 16 + lr]};
    float be2[2] = {beta[col0 + lr], beta[col0 + 16 + lr]};

    #pragma unroll
    for (int tt = 0; tt < RT; ++tt) {
        #pragma unroll
        for (int rr = 0; rr < 4; ++rr) {
            float sum = 0.f, sq = 0.f;
            #pragma unroll
            for (int c = 0; c < 2; ++c) {
                float v = fmaxf(acc2[tt][c][rr] + b2c[c], 0.f) + rp[tt][rr][c];
                acc2[tt][c][rr] = v;
                sum += v; sq += v * v;
            }
            sum += __shfl_xor(sum, 1); sq += __shfl_xor(sq, 1);
            sum += __shfl_xor(sum, 2); sq += __shfl_xor(sq, 2);
            sum += __shfl_xor(sum, 4); sq += __shfl_xor(sq, 4);
            sum += __shfl_xor(sum, 8); sq += __shfl_xor(sq, 8);
            if (lr == 0) {
                int rls = (roww << 4) + (lk << 2) + rr;
                lnbuf[((tt * 32 + rls) << 3) + (colw << 1) + 0] = sum;
                lnbuf[((tt * 32 + rls) << 3) + (colw << 1) + 1] = sq;
            }
        }
    }
    __syncthreads();
    #pragma unroll
    for (int tt = 0; tt < RT; ++tt) {
        #pragma unroll
        for (int rr = 0; rr < 4; ++rr) {
            int rls = (roww << 4) + (lk << 2) + rr;
            float s4 = 0.f, q4 = 0.f;
            #pragma unroll
            for (int cw = 0; cw < 4; ++cw) {
                s4 += lnbuf[((tt * 32 + rls) << 3) + (cw << 1) + 0];
                q4 += lnbuf[((tt * 32 + rls) << 3) + (cw << 1) + 1];
            }
            const float mean = s4 * (1.f / 128.f);
            const float var = q4 * (1.f / 128.f) - mean * mean;
            const float rs = rsqrtf(var + 1e-5f);
            int row = tbase + ((tt * RW + roww) << 4) + (lk << 2) + rr;
            if (row < M) {
                #pragma unroll
                for (int c = 0; c < 2; ++c)
                    Cf[(size_t)row * HH + col0 + (c << 4) + lr] =
                        (acc2[tt][c][rr] - mean) * rs * g2[c] + be2[c];
            }
        }
    }
}

// ---------------- fused K|V GEMM + score, CSR-ORDERED ----------------
template <int RT>
__global__ __launch_bounds__(512, 2) void kv_k(
    const unsigned short* __restrict__ hbf, const int* __restrict__ srcc,
    const unsigned short* __restrict__ ebfc,
    const unsigned short* __restrict__ Wt, const float* __restrict__ bias,
    const float* __restrict__ Q, const int* __restrict__ dstc,
    int M, unsigned short* __restrict__ V, float* __restrict__ sbuf)
{
    constexpr int ROWS = RT * 16;
    constexpr int Ktot = 256;
    constexpr int SI = ROWS / 32;
    __shared__ unsigned short Asl[2 * ROWS * 128];

    const int t = threadIdx.x;
    const int wid = t >> 6, lane = t & 63;
    const int lr = lane & 15, lk = lane >> 4;
    const int col0 = wid << 5;
    const int tbase = blockIdx.x * ROWS;

    int dstid[RT][4];
    if (wid < 4) {
        #pragma unroll
        for (int tt = 0; tt < RT; ++tt)
            #pragma unroll
            for (int rr = 0; rr < 4; ++rr) {
                int row = tbase + (tt << 4) + (lk << 2) + rr;
                dstid[tt][rr] = dstc[(row < M) ? row : M - 1];
            }
    }

    #pragma unroll
    for (int g = 0; g < 2; ++g) {
        const unsigned short* Ag = g ? ebfc : hbf;
        #pragma unroll
        for (int i = 0; i < SI; ++i) {
            int rl = ((i * 8 + wid) << 2) + (lane >> 4);
            int gr = tbase + rl; if (gr >= M) gr = M - 1;
            int rid = g ? gr : srcc[gr];     // e-chunk: contiguous CSR rows
            const unsigned short* srcp = Ag + (size_t)rid * HH + (((lane & 15) ^ (rl & 7)) << 3);
            unsigned short* dstp = &Asl[(g * ROWS + ((i * 8 + wid) << 2)) << 7];
            __builtin_amdgcn_global_load_lds((const __attribute__((address_space(1))) void*)srcp,
                                             (__attribute__((address_space(3))) void*)dstp, 16, 0, 0);
        }
    }

    f32x4 acc[RT][2];
    #pragma unroll
    for (int tt = 0; tt < RT; ++tt) { acc[tt][0] = (f32x4){0,0,0,0}; acc[tt][1] = (f32x4){0,0,0,0}; }

    __syncthreads();

    #pragma unroll
    for (int g = 0; g < 2; ++g) {
        bf16x8 b[4][2];
        #pragma unroll
        for (int s = 0; s < 4; ++s)
            #pragma unroll
            for (int c = 0; c < 2; ++c)
                b[s][c] = *(const bf16x8*)(Wt + (size_t)(col0 + (c << 4) + lr) * Ktot + (g << 7) + (s << 5) + (lk << 3));

        #pragma unroll
        for (int tt = 0; tt < RT; ++tt) {
            bf16x8 a[4];
            #pragma unroll
            for (int s = 0; s < 4; ++s) {
                const int c16 = ((s << 2) + lk) ^ (lr & 7);
                a[s] = *(const bf16x8*)&Asl[((g * ROWS + (tt << 4) + lr) << 7) + (c16 << 3)];
            }
            #pragma unroll
            for (int s = 0; s < 4; ++s) {
                acc[tt][0] = __builtin_amdgcn_mfma_f32_16x16x32_bf16(a[s], b[s][0], acc[tt][0], 0, 0, 0);
                acc[tt][1] = __builtin_amdgcn_mfma_f32_16x16x32_bf16(a[s], b[s][1], acc[tt][1], 0, 0, 0);
            }
        }
    }

    float bias2[2] = {bias[col0 + lr], bias[col0 + 16 + lr]};

    if (wid < 4) {
        #pragma unroll
        for (int tt = 0; tt < RT; ++tt) {
            #pragma unroll
            for (int rr = 0; rr < 4; ++rr) {
                int row = tbase + (tt << 4) + (lk << 2) + rr;
                int d = dstid[tt][rr];
                float q0 = Q[(size_t)d * HH + col0 + lr];
                float q1 = Q[(size_t)d * HH + col0 + 16 + lr];
                float p = (acc[tt][0][rr] + bias2[0]) * q0 + (acc[tt][1][rr] + bias2[1]) * q1;
                p += __shfl_xor(p, 1); p += __shfl_xor(p, 2);
                p += __shfl_xor(p, 4); p += __shfl_xor(p, 8);
                if (lr == 0 && row < M)
                    sbuf[(size_t)row * 4 + wid] = p * 0.17677669529663687f;
            }
        }
    } else {
        #pragma unroll
        for (int tt = 0; tt < RT; ++tt) {
            #pragma unroll
            for (int rr = 0; rr < 4; ++rr) {
                int row = tbase + (tt << 4) + (lk << 2) + rr;
                if (row >= M) continue;
                #pragma unroll
                for (int c = 0; c < 2; ++c)
                    V[(size_t)row * HH + (col0 - 128) + (c << 4) + lr] = f2bf(acc[tt][c][rr] + bias2[c]);
            }
        }
    }
}

// ---------------- per-node online-softmax aggregation (CSR-streaming, vectorized) ----------------
__global__ __launch_bounds__(256) void agg_k(const unsigned short* __restrict__ Vb,
                                             const float* __restrict__ s,
                                             const int* __restrict__ offsets,
                                             unsigned short* __restrict__ hagg)
{
    const int t = threadIdx.x;
    const int n = blockIdx.x * 4 + (t >> 6);
    if (n >= NN) return;
    const int lane = t & 63;
    const int c = lane << 1;
    const int h = lane >> 4;
    const int o0 = offsets[n], o1 = offsets[n + 1];
    float m = -1e30f, d = 0.f, a0 = 0.f, a1 = 0.f;
    for (int j = o0; j < o1; ++j) {
        const float sj = s[(size_t)j * 4 + h];
        ushort2 vv = *(const ushort2*)(Vb + (size_t)j * HH + c);
        float nm = fmaxf(m, sj);
        float sc = __expf(m - nm);
        float w  = __expf(sj - nm);
        d = d * sc + w;
        a0 = a0 * sc + w * bf2f(vv.x);
        a1 = a1 * sc + w * bf2f(vv.y);
        m = nm;
    }
    const bool any = (o1 > o0);
    ushort2 o;
    o.x = any ? f2bf(a0 / d) : 0;
    o.y = any ? f2bf(a1 / d) : 0;
    *(ushort2*)(hagg + (size_t)n * HH + c) = o;
}

extern "C" void kernel_launch(void* const* d_in, const int* in_sizes, int n_in,
                              void* d_out, int out_size, void* d_ws, size_t ws_size,
                              hipStream_t stream)
{
    const float* h   = (const float*)d_in[0];
    const float* e   = (const float*)d_in[1];
    const int*   src = (const int*)d_in[2];
    const int*   dst = (const int*)d_in[3];
    const float* Wq  = (const float*)d_in[4];
    const float* bq  = (const float*)d_in[5];
    const float* Wk  = (const float*)d_in[6];
    const float* bk  = (const float*)d_in[7];
    const float* Wv  = (const float*)d_in[8];
    const float* bv  = (const float*)d_in[9];
    const float* Wn1 = (const float*)d_in[10];
    const float* bn1 = (const float*)d_in[11];
    const float* Wn2 = (const float*)d_in[12];
    const float* bn2 = (const float*)d_in[13];
    const float* We1 = (const float*)d_in[14];
    const float* be1 = (const float*)d_in[15];
    const float* We2 = (const float*)d_in[16];
    const float* be2 = (const float*)d_in[17];
    const float* gh  = (const float*)d_in[18];
    const float* bh  = (const float*)d_in[19];
    const float* ge  = (const float*)d_in[20];
    const float* be_ = (const float*)d_in[21];
    (void)in_sizes; (void)n_in; (void)out_size; (void)ws_size;

    float* h_out = (float*)d_out;
    float* e_out = (float*)d_out + (size_t)NN * HH;

    char* ws = (char*)d_ws;
    size_t off = 0;
    auto carve = [&](size_t bytes) { void* p = ws + off; off += (bytes + 255) & ~(size_t)255; return p; };
    unsigned short* Vbuf = (unsigned short*)carve((size_t)EE * HH * 2);   // V bf16, CSR order
    unsigned short* ebfc = (unsigned short*)carve((size_t)EE * HH * 2);   // e bf16, CSR order
    float* Q      = (float*)carve((size_t)NN * HH * 4);
    float* sbuf   = (float*)carve((size_t)EE * 4 * 4);                    // scores, CSR order
    unsigned short* hagg = (unsigned short*)carve((size_t)NN * HH * 2);
    unsigned short* hobf = (unsigned short*)carve((size_t)NN * HH * 2);
    unsigned short* hbf  = (unsigned short*)carve((size_t)NN * HH * 2);
    int* cursor   = (int*)carve((size_t)NN * 4);
    int* offsets  = (int*)carve((size_t)(NN + 1) * 4);
    int* bsum     = (int*)carve(256 * 4);
    int* eids     = (int*)carve((size_t)EE * 4);
    int* srcc     = (int*)carve((size_t)EE * 4);
    int* dstc     = (int*)carve((size_t)EE * 4);
    unsigned short* Wq_s  = (unsigned short*)carve(128 * 128 * 2);
    unsigned short* Wkv_s = (unsigned short*)carve(256 * 256 * 2);
    unsigned short* Wn1_s = (unsigned short*)carve(128 * 128 * 2);
    unsigned short* Wn2_s = (unsigned short*)carve(128 * 128 * 2);
    unsigned short* We1_s = (unsigned short*)carve(128 * 384 * 2);
    unsigned short* We2_s = (unsigned short*)carve(128 * 128 * 2);
    float* b_kv   = (float*)carve(256 * 4);

    const int nb = (NN + 255) / 256;

    // weight prep (bf16 transpose) + combined KV bias
    wprep_k<<<(128 * 128 + 255) / 256, 256, 0, stream>>>(Wq,  Wq_s,  128, 128, 0, 128);
    wprep_k<<<(256 * 128 + 255) / 256, 256, 0, stream>>>(Wk,  Wkv_s, 256, 128, 0, 256);
    wprep_k<<<(256 * 128 + 255) / 256, 256, 0, stream>>>(Wv,  Wkv_s, 256, 128, 128, 256);
    wprep_k<<<(128 * 128 + 255) / 256, 256, 0, stream>>>(Wn1, Wn1_s, 128, 128, 0, 128);
    wprep_k<<<(128 * 128 + 255) / 256, 256, 0, stream>>>(Wn2, Wn2_s, 128, 128, 0, 128);
    wprep_k<<<(384 * 128 + 255) / 256, 256, 0, stream>>>(We1, We1_s, 384, 128, 0, 384);
    wprep_k<<<(128 * 128 + 255) / 256, 256, 0, stream>>>(We2, We2_s, 128, 128, 0, 128);
    hipMemcpyAsync(b_kv,       bk, 128 * 4, hipMemcpyDeviceToDevice, stream);
    hipMemcpyAsync(b_kv + 128, bv, 128 * 4, hipMemcpyDeviceToDevice, stream);

    // h -> bf16
    cvt_k<<<(NN * HH / 8 + 255) / 256, 256, 0, stream>>>(h, hbf, (long)NN * HH / 8);

    // CSR build (+ CSR-ordered src/dst)
    hipMemsetAsync(cursor, 0, (size_t)NN * 4, stream);
    hist_k<<<(EE + 255) / 256, 256, 0, stream>>>(dst, cursor);
    blocksum_k<<<nb, 256, 0, stream>>>(cursor, bsum);
    scanb_k<<<1, 256, 0, stream>>>(bsum, nb);
    offsets_k<<<nb, 256, 0, stream>>>(cursor, bsum, offsets, cursor);
    fill_k<<<(EE + 255) / 256, 256, 0, stream>>>(src, dst, cursor, eids, srcc, dstc);

    // e -> bf16 in CSR order (kv's e-stage becomes contiguous)
    cvtcsr_k<<<(EE * 16 + 255) / 256, 256, 0, stream>>>(e, eids, ebfc);

    // Q = h @ Wq + bq  (f32 out)
    mm4_k<1, 4, 4, 0><<<(NN + 127) / 128, 512, 0, stream>>>(
        hbf, nullptr, Wq_s, bq, NN, Q, nullptr, 128);

    // fused K|V GEMM + score in CSR order
    kv_k<4><<<EE / 64, 512, 0, stream>>>(
        hbf, srcc, ebfc, Wkv_s, b_kv, Q, dstc, EE, Vbuf, sbuf);

    agg_k<<<(NN + 3) / 4, 256, 0, stream>>>(Vbuf, sbuf, offsets, hagg);

    // fused node MLP (emits h_out f32 + hobf bf16)
    mlp_k<1, 4><<<(NN + 127) / 128, 512, 0, stream>>>(
        hagg, nullptr, Wn1_s, bn1, Wn2_s, bn2, NN, h_out, hobf, h, gh, bh);

    // fused edge MLP: e staged once as f32; deduped in-place bf16 conversion
    mlpe_k<<<EE / 64, 512, 0, stream>>>(
        hobf, src, dst, e, We1_s, be1, We2_s, be2, EE, e_out, ge, be_);
}

// Round 17
// 1239.146 us; speedup vs baseline: 1.0264x; 1.0264x over previous
//
#include <hip/hip_runtime.h>
#include <hip/hip_bf16.h>

#define NN 50000
#define EE 800000
#define HH 128

typedef __attribute__((ext_vector_type(8))) short bf16x8;
typedef __attribute__((ext_vector_type(4))) float f32x4;

__device__ inline unsigned short f2bf(float f) {
    union { float f; unsigned u; } v; v.f = f;
    unsigned r = v.u + 0x7FFF + ((v.u >> 16) & 1);
    return (unsigned short)(r >> 16);
}
__device__ inline float bf2f(unsigned short u) {
    union { unsigned u32; float f; } v; v.u32 = (unsigned)u << 16; return v.f;
}

// ---------------- CSR build (edges grouped by dst) ----------------
__global__ __launch_bounds__(256) void hist_k(const int* __restrict__ dst, int* __restrict__ cnt) {
    int i = blockIdx.x * 256 + threadIdx.x;
    if (i < EE) atomicAdd(&cnt[dst[i]], 1);
}

__global__ __launch_bounds__(256) void blocksum_k(const int* __restrict__ cnt, int* __restrict__ bsum) {
    __shared__ int sm[256];
    int i = blockIdx.x * 256 + threadIdx.x;
    sm[threadIdx.x] = (i < NN) ? cnt[i] : 0;
    __syncthreads();
    for (int s = 128; s > 0; s >>= 1) {
        if (threadIdx.x < s) sm[threadIdx.x] += sm[threadIdx.x + s];
        __syncthreads();
    }
    if (threadIdx.x == 0) bsum[blockIdx.x] = sm[0];
}

__global__ __launch_bounds__(256) void scanb_k(int* __restrict__ bsum, int nb) {
    __shared__ int sm[256];
    int t = threadIdx.x;
    sm[t] = (t < nb) ? bsum[t] : 0;
    __syncthreads();
    for (int d = 1; d < 256; d <<= 1) {
        int v = (t >= d) ? sm[t - d] : 0;
        __syncthreads();
        sm[t] += v;
        __syncthreads();
    }
    if (t < nb) bsum[t] = sm[t];
}

__global__ __launch_bounds__(256) void offsets_k(const int* __restrict__ cnt, const int* __restrict__ bsum,
                                                 int* __restrict__ offsets, int* __restrict__ cursor) {
    __shared__ int sm[256];
    int b = blockIdx.x, t = threadIdx.x;
    int i = b * 256 + t;
    int c = (i < NN) ? cnt[i] : 0;
    sm[t] = c;
    __syncthreads();
    for (int d = 1; d < 256; d <<= 1) {
        int v = (t >= d) ? sm[t - d] : 0;
        __syncthreads();
        sm[t] += v;
        __syncthreads();
    }
    int incl = sm[t];
    int base = (b == 0) ? 0 : bsum[b - 1];
    int off = base + incl - c;
    if (i < NN) { offsets[i] = off; cursor[i] = off; }
    if (i == NN - 1) offsets[NN] = off + c;
}

// fill CSR edge list; also materialize CSR-ordered src/dst
__global__ __launch_bounds__(256) void fill_k(const int* __restrict__ src, const int* __restrict__ dst,
                                              int* __restrict__ cursor, int* __restrict__ eids,
                                              int* __restrict__ srcc, int* __restrict__ dstc) {
    int i = blockIdx.x * 256 + threadIdx.x;
    if (i < EE) {
        int d = dst[i];
        int p = atomicAdd(&cursor[d], 1);
        eids[p] = i;
        srcc[p] = src[i];
        dstc[p] = d;
    }
}

// ---------------- weight prep: W[fi][fo] f32 -> W_t[n][k] bf16 (plain transpose) ----------------
__global__ __launch_bounds__(256) void wprep_k(const float* __restrict__ W, unsigned short* __restrict__ out,
                                               int fi, int fo, int n_off, int out_ld) {
    int i = blockIdx.x * 256 + threadIdx.x;
    if (i >= fi * fo) return;
    int n = i / fi, k = i - n * fi;
    out[(size_t)(n_off + n) * out_ld + k] = f2bf(W[(size_t)k * fo + n]);
}

// ---------------- f32 -> bf16 bulk convert (8 elems/thread) ----------------
__global__ __launch_bounds__(256) void cvt_k(const float* __restrict__ in, unsigned short* __restrict__ out,
                                             long n8) {
    long i = (long)blockIdx.x * 256 + threadIdx.x;
    if (i >= n8) return;
    const float4* p = (const float4*)in + i * 2;
    float4 a = p[0], b = p[1];
    bf16x8 o = {(short)f2bf(a.x), (short)f2bf(a.y), (short)f2bf(a.z), (short)f2bf(a.w),
                (short)f2bf(b.x), (short)f2bf(b.y), (short)f2bf(b.z), (short)f2bf(b.w)};
    *((bf16x8*)out + i) = o;
}

// ---------------- CSR-ordered bf16 copy of e ----------------
__global__ __launch_bounds__(256) void cvtcsr_k(const float* __restrict__ e, const int* __restrict__ eids,
                                                unsigned short* __restrict__ out) {
    long gid = (long)blockIdx.x * 256 + threadIdx.x;
    long j = gid >> 4;
    if (j >= EE) return;
    int part = (int)(gid & 15);
    int rid = eids[j];
    const float4* p = (const float4*)(e + (size_t)rid * HH + part * 8);
    float4 a = p[0], b = p[1];
    bf16x8 o = {(short)f2bf(a.x), (short)f2bf(a.y), (short)f2bf(a.z), (short)f2bf(a.w),
                (short)f2bf(b.x), (short)f2bf(b.y), (short)f2bf(b.z), (short)f2bf(b.w)};
    *((bf16x8*)(out + (size_t)j * HH + part * 8)) = o;
}

// ---------------- single-barrier MFMA gather-GEMM (used for Q) ----------------
template <int G, int NCW, int RT, int MODE>
__global__ __launch_bounds__(512, 2) void mm4_k(
    const unsigned short* __restrict__ A0, const int* __restrict__ idx0,
    const unsigned short* __restrict__ Wt, const float* __restrict__ bias,
    int M,
    float* __restrict__ Cf, unsigned short* __restrict__ Cb, int out_ld)
{
    constexpr int RW = 8 / NCW;
    constexpr int ROWS = RW * RT * 16;
    constexpr int Ktot = G * 128;
    constexpr int SI = ROWS / 32;
    __shared__ unsigned short Asl[G * ROWS * 128];

    const int t = threadIdx.x;
    const int wid = t >> 6, lane = t & 63;
    const int lr = lane & 15, lk = lane >> 4;
    const int colw = wid & 3;
    const int roww = wid >> 2;
    const int col0 = colw << 5;
    const int tbase = blockIdx.x * ROWS;

    #pragma unroll
    for (int g = 0; g < G; ++g) {
        #pragma unroll
        for (int i = 0; i < SI; ++i) {
            int rl = ((i * 8 + wid) << 2) + (lane >> 4);
            int gr = tbase + rl; if (gr >= M) gr = M - 1;
            int rid = idx0 ? idx0[gr] : gr;
            const unsigned short* src = A0 + (size_t)rid * HH + (((lane & 15) ^ (rl & 7)) << 3);
            unsigned short* dst = &Asl[(g * ROWS + ((i * 8 + wid) << 2)) << 7];
            __builtin_amdgcn_global_load_lds((const __attribute__((address_space(1))) void*)src,
                                             (__attribute__((address_space(3))) void*)dst, 16, 0, 0);
        }
    }

    f32x4 acc[RT][2];
    #pragma unroll
    for (int tt = 0; tt < RT; ++tt) { acc[tt][0] = (f32x4){0,0,0,0}; acc[tt][1] = (f32x4){0,0,0,0}; }

    __syncthreads();

    #pragma unroll
    for (int g = 0; g < G; ++g) {
        bf16x8 b[4][2];
        #pragma unroll
        for (int s = 0; s < 4; ++s)
            #pragma unroll
            for (int c = 0; c < 2; ++c)
                b[s][c] = *(const bf16x8*)(Wt + (size_t)(col0 + (c << 4) + lr) * Ktot + (g << 7) + (s << 5) + (lk << 3));

        #pragma unroll
        for (int tt = 0; tt < RT; ++tt) {
            const int tl = (tt * RW + roww) << 4;
            bf16x8 a[4];
            #pragma unroll
            for (int s = 0; s < 4; ++s) {
                const int c16 = ((s << 2) + lk) ^ (lr & 7);
                a[s] = *(const bf16x8*)&Asl[((g * ROWS + tl + lr) << 7) + (c16 << 3)];
            }
            #pragma unroll
            for (int s = 0; s < 4; ++s) {
                acc[tt][0] = __builtin_amdgcn_mfma_f32_16x16x32_bf16(a[s], b[s][0], acc[tt][0], 0, 0, 0);
                acc[tt][1] = __builtin_amdgcn_mfma_f32_16x16x32_bf16(a[s], b[s][1], acc[tt][1], 0, 0, 0);
            }
        }
    }

    float bias2[2] = {bias[col0 + lr], bias[col0 + 16 + lr]};
    #pragma unroll
    for (int tt = 0; tt < RT; ++tt) {
        #pragma unroll
        for (int rr = 0; rr < 4; ++rr) {
            int row = tbase + ((tt * RW + roww) << 4) + (lk << 2) + rr;
            if (row >= M) continue;
            #pragma unroll
            for (int c = 0; c < 2; ++c) {
                float v = acc[tt][c][rr] + bias2[c];
                if (MODE == 1) v = fmaxf(v, 0.f);
                size_t o = (size_t)row * out_ld + col0 + (c << 4) + lr;
                if (MODE == 0 || MODE == 1) Cf[o] = v;
                else Cb[o] = f2bf(v);
            }
        }
    }
}

// ---------------- fused 2-layer MLP + resid + LN (node version) ----------------
template <int G, int RT>
__global__ __launch_bounds__(512, 2) void mlp_k(
    const unsigned short* __restrict__ A0, const int* __restrict__ idx0,
    const unsigned short* __restrict__ W1t, const float* __restrict__ b1,
    const unsigned short* __restrict__ W2t, const float* __restrict__ b2,
    int M,
    float* __restrict__ Cf, unsigned short* __restrict__ Cb2,
    const float* __restrict__ resid, const float* __restrict__ gamma, const float* __restrict__ beta)
{
    constexpr int RW = 2, NCW = 4;
    constexpr int ROWS = RW * RT * 16;
    constexpr int K1 = G * 128;
    constexpr int SI = ROWS / 32;
    __shared__ unsigned short Asl[G * ROWS * 128];   // first ROWS*128 shorts reused as t-buffer
    __shared__ float lnbuf[RT * 32 * 8];

    const int t = threadIdx.x;
    const int wid = t >> 6, lane = t & 63;
    const int lr = lane & 15, lk = lane >> 4;
    const int colw = wid & 3, roww = wid >> 2;
    const int col0 = colw << 5;
    const int tbase = blockIdx.x * ROWS;

    #pragma unroll
    for (int g = 0; g < G; ++g) {
        #pragma unroll
        for (int i = 0; i < SI; ++i) {
            int rl = ((i * 8 + wid) << 2) + (lane >> 4);
            int gr = tbase + rl; if (gr >= M) gr = M - 1;
            int rid = idx0 ? idx0[gr] : gr;
            const unsigned short* src = A0 + (size_t)rid * HH + (((lane & 15) ^ (rl & 7)) << 3);
            unsigned short* dst = &Asl[(g * ROWS + ((i * 8 + wid) << 2)) << 7];
            __builtin_amdgcn_global_load_lds((const __attribute__((address_space(1))) void*)src,
                                             (__attribute__((address_space(3))) void*)dst, 16, 0, 0);
        }
    }

    f32x4 acc[RT][2];
    #pragma unroll
    for (int tt = 0; tt < RT; ++tt) { acc[tt][0] = (f32x4){0,0,0,0}; acc[tt][1] = (f32x4){0,0,0,0}; }

    __syncthreads();

    #pragma unroll
    for (int g = 0; g < G; ++g) {
        bf16x8 b[4][2];
        #pragma unroll
        for (int s = 0; s < 4; ++s)
            #pragma unroll
            for (int c = 0; c < 2; ++c)
                b[s][c] = *(const bf16x8*)(W1t + (size_t)(col0 + (c << 4) + lr) * K1 + (g << 7) + (s << 5) + (lk << 3));

        #pragma unroll
        for (int tt = 0; tt < RT; ++tt) {
            const int tl = (tt * RW + roww) << 4;
            bf16x8 a[4];
            #pragma unroll
            for (int s = 0; s < 4; ++s) {
                const int c16 = ((s << 2) + lk) ^ (lr & 7);
                a[s] = *(const bf16x8*)&Asl[((g * ROWS + tl + lr) << 7) + (c16 << 3)];
            }
            #pragma unroll
            for (int s = 0; s < 4; ++s) {
                acc[tt][0] = __builtin_amdgcn_mfma_f32_16x16x32_bf16(a[s], b[s][0], acc[tt][0], 0, 0, 0);
                acc[tt][1] = __builtin_amdgcn_mfma_f32_16x16x32_bf16(a[s], b[s][1], acc[tt][1], 0, 0, 0);
            }
        }
    }

    __syncthreads();

    {
        float b1c[2] = {b1[col0 + lr], b1[col0 + 16 + lr]};
        #pragma unroll
        for (int tt = 0; tt < RT; ++tt) {
            #pragma unroll
            for (int rr = 0; rr < 4; ++rr) {
                int rowl = ((tt * RW + roww) << 4) + (lk << 2) + rr;
                #pragma unroll
                for (int c = 0; c < 2; ++c) {
                    int col = col0 + (c << 4) + lr;
                    int chunk = (col >> 3) ^ (rowl & 7);
                    Asl[(rowl << 7) + (chunk << 3) + (col & 7)] =
                        f2bf(fmaxf(acc[tt][c][rr] + b1c[c], 0.f));
                }
            }
        }
    }

    __syncthreads();

    f32x4 acc2[RT][2];
    #pragma unroll
    for (int tt = 0; tt < RT; ++tt) { acc2[tt][0] = (f32x4){0,0,0,0}; acc2[tt][1] = (f32x4){0,0,0,0}; }

    {
        bf16x8 b[4][2];
        #pragma unroll
        for (int s = 0; s < 4; ++s)
            #pragma unroll
            for (int c = 0; c < 2; ++c)
                b[s][c] = *(const bf16x8*)(W2t + (size_t)(col0 + (c << 4) + lr) * 128 + (s << 5) + (lk << 3));

        #pragma unroll
        for (int tt = 0; tt < RT; ++tt) {
            const int tl = (tt * RW + roww) << 4;
            bf16x8 a[4];
            #pragma unroll
            for (int s = 0; s < 4; ++s) {
                const int c16 = ((s << 2) + lk) ^ (lr & 7);
                a[s] = *(const bf16x8*)&Asl[((tl + lr) << 7) + (c16 << 3)];
            }
            #pragma unroll
            for (int s = 0; s < 4; ++s) {
                acc2[tt][0] = __builtin_amdgcn_mfma_f32_16x16x32_bf16(a[s], b[s][0], acc2[tt][0], 0, 0, 0);
                acc2[tt][1] = __builtin_amdgcn_mfma_f32_16x16x32_bf16(a[s], b[s][1], acc2[tt][1], 0, 0, 0);
            }
        }
    }

    float b2c[2] = {b2[col0 + lr], b2[col0 + 16 + lr]};
    float g2[2] = {gamma[col0 + lr], gamma[col0 + 16 + lr]};
    float be2[2] = {beta[col0 + lr], beta[col0 + 16 + lr]};

    #pragma unroll
    for (int tt = 0; tt < RT; ++tt) {
        #pragma unroll
        for (int rr = 0; rr < 4; ++rr) {
            int row = tbase + ((tt * RW + roww) << 4) + (lk << 2) + rr;
            int rowc = (row < M) ? row : M - 1;
            float sum = 0.f, sq = 0.f;
            #pragma unroll
            for (int c = 0; c < 2; ++c) {
                float v = fmaxf(acc2[tt][c][rr] + b2c[c], 0.f);
                v += resid[(size_t)rowc * HH + col0 + (c << 4) + lr];
                acc2[tt][c][rr] = v;
                sum += v; sq += v * v;
            }
            sum += __shfl_xor(sum, 1); sq += __shfl_xor(sq, 1);
            sum += __shfl_xor(sum, 2); sq += __shfl_xor(sq, 2);
            sum += __shfl_xor(sum, 4); sq += __shfl_xor(sq, 4);
            sum += __shfl_xor(sum, 8); sq += __shfl_xor(sq, 8);
            if (lr == 0) {
                int rls = (roww << 4) + (lk << 2) + rr;
                lnbuf[((tt * 32 + rls) << 3) + (colw << 1) + 0] = sum;
                lnbuf[((tt * 32 + rls) << 3) + (colw << 1) + 1] = sq;
            }
        }
    }
    __syncthreads();
    #pragma unroll
    for (int tt = 0; tt < RT; ++tt) {
        #pragma unroll
        for (int rr = 0; rr < 4; ++rr) {
            int rls = (roww << 4) + (lk << 2) + rr;
            float s4 = 0.f, q4 = 0.f;
            #pragma unroll
            for (int cw = 0; cw < 4; ++cw) {
                s4 += lnbuf[((tt * 32 + rls) << 3) + (cw << 1) + 0];
                q4 += lnbuf[((tt * 32 + rls) << 3) + (cw << 1) + 1];
            }
            const float mean = s4 * (1.f / 128.f);
            const float var = q4 * (1.f / 128.f) - mean * mean;
            const float rs = rsqrtf(var + 1e-5f);
            int row = tbase + ((tt * RW + roww) << 4) + (lk << 2) + rr;
            if (row < M) {
                #pragma unroll
                for (int c = 0; c < 2; ++c) {
                    float o = (acc2[tt][c][rr] - mean) * rs * g2[c] + be2[c];
                    size_t idx = (size_t)row * HH + col0 + (c << 4) + lr;
                    Cf[idx] = o;
                    if (Cb2) Cb2[idx] = f2bf(o);
                }
            }
        }
    }
}

// ---------------- EDGE MLP: e staged ONCE as f32 (GEMM input + residual) ----------------
__global__ __launch_bounds__(512, 2) void mlpe_k(
    const unsigned short* __restrict__ ho, const int* __restrict__ src,
    const int* __restrict__ dst, const float* __restrict__ e,
    const unsigned short* __restrict__ W1t, const float* __restrict__ b1,
    const unsigned short* __restrict__ W2t, const float* __restrict__ b2,
    int M,
    float* __restrict__ Cf,
    const float* __restrict__ gamma, const float* __restrict__ beta)
{
    constexpr int RW = 2, RT = 2;
    constexpr int ROWS = RW * RT * 16;      // 64
    constexpr int K1 = 384;
    __shared__ unsigned short Asl[2 * ROWS * 128];  // chunks 0,1 (bf16); chunk0 reused as t-buffer
    __shared__ float Esl[ROWS * 128];               // e rows f32, 16B-chunk swizzled
    __shared__ float lnbuf[RT * 32 * 8];

    const int t = threadIdx.x;
    const int wid = t >> 6, lane = t & 63;
    const int lr = lane & 15, lk = lane >> 4;
    const int colw = wid & 3, roww = wid >> 2;
    const int col0 = colw << 5;
    const int tbase = blockIdx.x * ROWS;

    // ---- stage bf16 chunks: ho[src], ho[dst] ----
    #pragma unroll
    for (int g = 0; g < 2; ++g) {
        const int* ig = g ? dst : src;
        #pragma unroll
        for (int i = 0; i < 2; ++i) {
            int rl = ((i * 8 + wid) << 2) + (lane >> 4);
            int gr = tbase + rl; if (gr >= M) gr = M - 1;
            int rid = ig[gr];
            const unsigned short* sp = ho + (size_t)rid * HH + (((lane & 15) ^ (rl & 7)) << 3);
            unsigned short* dp = &Asl[(g * ROWS + ((i * 8 + wid) << 2)) << 7];
            __builtin_amdgcn_global_load_lds((const __attribute__((address_space(1))) void*)sp,
                                             (__attribute__((address_space(3))) void*)dp, 16, 0, 0);
        }
    }
    // ---- stage e rows f32 (source 16B-chunk swizzled; LDS dest linear) ----
    #pragma unroll
    for (int i = 0; i < 4; ++i) {
        int row = i * 16 + wid * 2 + (lane >> 5);
        int c16 = lane & 31;
        int c16s = (c16 & 24) | ((c16 & 7) ^ (row & 7));
        int gr = tbase + row; if (gr >= M) gr = M - 1;
        const float* sp = e + (size_t)gr * HH + c16s * 4;
        float* dbase = Esl + (size_t)(i * 512 + wid * 64) * 4;
        __builtin_amdgcn_global_load_lds((const __attribute__((address_space(1))) void*)sp,
                                         (__attribute__((address_space(3))) void*)dbase, 16, 0, 0);
    }

    f32x4 acc[RT][2];
    #pragma unroll
    for (int tt = 0; tt < RT; ++tt) { acc[tt][0] = (f32x4){0,0,0,0}; acc[tt][1] = (f32x4){0,0,0,0}; }

    __syncthreads();

    // ---- GEMM1 over K=384: chunks 0,1 bf16; chunk 2 from Esl (f32 -> f2bf) ----
    #pragma unroll
    for (int g = 0; g < 3; ++g) {
        bf16x8 b[4][2];
        #pragma unroll
        for (int s = 0; s < 4; ++s)
            #pragma unroll
            for (int c = 0; c < 2; ++c)
                b[s][c] = *(const bf16x8*)(W1t + (size_t)(col0 + (c << 4) + lr) * K1 + (g << 7) + (s << 5) + (lk << 3));

        #pragma unroll
        for (int tt = 0; tt < RT; ++tt) {
            const int tl = (tt * RW + roww) << 4;
            const int r = tl + lr;
            bf16x8 a[4];
            if (g < 2) {
                #pragma unroll
                for (int s = 0; s < 4; ++s) {
                    const int c16 = ((s << 2) + lk) ^ (lr & 7);
                    a[s] = *(const bf16x8*)&Asl[((g * ROWS + r) << 7) + (c16 << 3)];
                }
            } else {
                #pragma unroll
                for (int s = 0; s < 4; ++s) {
                    int c16a = (s << 3) + (lk << 1);
                    int c16b = c16a + 1;
                    int ca = (c16a & 24) | ((c16a & 7) ^ (r & 7));
                    int cb = (c16b & 24) | ((c16b & 7) ^ (r & 7));
                    float4 fa = *(const float4*)&Esl[r * 128 + ca * 4];
                    float4 fb = *(const float4*)&Esl[r * 128 + cb * 4];
                    a[s] = (bf16x8){(short)f2bf(fa.x), (short)f2bf(fa.y), (short)f2bf(fa.z), (short)f2bf(fa.w),
                                    (short)f2bf(fb.x), (short)f2bf(fb.y), (short)f2bf(fb.z), (short)f2bf(fb.w)};
                }
            }
            #pragma unroll
            for (int s = 0; s < 4; ++s) {
                acc[tt][0] = __builtin_amdgcn_mfma_f32_16x16x32_bf16(a[s], b[s][0], acc[tt][0], 0, 0, 0);
                acc[tt][1] = __builtin_amdgcn_mfma_f32_16x16x32_bf16(a[s], b[s][1], acc[tt][1], 0, 0, 0);
            }
        }
    }

    __syncthreads();   // all chunk-0 reads done; t-buffer may overwrite it

    // ---- t = relu(acc + b1) -> LDS bf16 (chunk-0 region, XOR-swizzled) ----
    {
        float b1c[2] = {b1[col0 + lr], b1[col0 + 16 + lr]};
        #pragma unroll
        for (int tt = 0; tt < RT; ++tt) {
            #pragma unroll
            for (int rr = 0; rr < 4; ++rr) {
                int rowl = ((tt * RW + roww) << 4) + (lk << 2) + rr;
                #pragma unroll
                for (int c = 0; c < 2; ++c) {
                    int col = col0 + (c << 4) + lr;
                    int chunk = (col >> 3) ^ (rowl & 7);
                    Asl[(rowl << 7) + (chunk << 3) + (col & 7)] =
                        f2bf(fmaxf(acc[tt][c][rr] + b1c[c], 0.f));
                }
            }
        }
    }

    __syncthreads();

    // ---- GEMM2: t @ W2 ----
    f32x4 acc2[RT][2];
    #pragma unroll
    for (int tt = 0; tt < RT; ++tt) { acc2[tt][0] = (f32x4){0,0,0,0}; acc2[tt][1] = (f32x4){0,0,0,0}; }

    {
        bf16x8 b[4][2];
        #pragma unroll
        for (int s = 0; s < 4; ++s)
            #pragma unroll
            for (int c = 0; c < 2; ++c)
                b[s][c] = *(const bf16x8*)(W2t + (size_t)(col0 + (c << 4) + lr) * 128 + (s << 5) + (lk << 3));

        #pragma unroll
        for (int tt = 0; tt < RT; ++tt) {
            const int tl = (tt * RW + roww) << 4;
            bf16x8 a[4];
            #pragma unroll
            for (int s = 0; s < 4; ++s) {
                const int c16 = ((s << 2) + lk) ^ (lr & 7);
                a[s] = *(const bf16x8*)&Asl[((tl + lr) << 7) + (c16 << 3)];
            }
            #pragma unroll
            for (int s = 0; s < 4; ++s) {
                acc2[tt][0] = __builtin_amdgcn_mfma_f32_16x16x32_bf16(a[s], b[s][0], acc2[tt][0], 0, 0, 0);
                acc2[tt][1] = __builtin_amdgcn_mfma_f32_16x16x32_bf16(a[s], b[s][1], acc2[tt][1], 0, 0, 0);
            }
        }
    }

    // ---- LN epilogue: residual read from Esl (f32, swizzled) ----
    float b2c[2] = {b2[col0 + lr], b2[col0 + 16 + lr]};
    float g2[2] = {gamma[col0 + lr], gamma[col0 + 16 + lr]};
    float be2[2] = {beta[col0 + lr], beta[col0 + 16 + lr]};

    #pragma unroll
    for (int tt = 0; tt < RT; ++tt) {
        #pragma unroll
        for (int rr = 0; rr < 4; ++rr) {
            int rowl = ((tt * RW + roww) << 4) + (lk << 2) + rr;
            float sum = 0.f, sq = 0.f;
            #pragma unroll
            for (int c = 0; c < 2; ++c) {
                int col = col0 + (c << 4) + lr;
                int c16 = col >> 2;
                int cs = (c16 & 24) | ((c16 & 7) ^ (rowl & 7));
                float rv = Esl[rowl * 128 + cs * 4 + (col & 3)];
                float v = fmaxf(acc2[tt][c][rr] + b2c[c], 0.f) + rv;
                acc2[tt][c][rr] = v;
                sum += v; sq += v * v;
            }
            sum += __shfl_xor(sum, 1); sq += __shfl_xor(sq, 1);
            sum += __shfl_xor(sum, 2); sq += __shfl_xor(sq, 2);
            sum += __shfl_xor(sum, 4); sq += __shfl_xor(sq, 4);
            sum += __shfl_xor(sum, 8); sq += __shfl_xor(sq, 8);
            if (lr == 0) {
                int rls = (roww << 4) + (lk << 2) + rr;
                lnbuf[((tt * 32 + rls) << 3) + (colw << 1) + 0] = sum;
                lnbuf[((tt * 32 + rls) << 3) + (colw << 1) + 1] = sq;
            }
        }
    }
    __syncthreads();
    #pragma unroll
    for (int tt = 0; tt < RT; ++tt) {
        #pragma unroll
        for (int rr = 0; rr < 4; ++rr) {
            int rls = (roww << 4) + (lk << 2) + rr;
            float s4 = 0.f, q4 = 0.f;
            #pragma unroll
            for (int cw = 0; cw < 4; ++cw) {
                s4 += lnbuf[((tt * 32 + rls) << 3) + (cw << 1) + 0];
                q4 += lnbuf[((tt * 32 + rls) << 3) + (cw << 1) + 1];
            }
            const float mean = s4 * (1.f / 128.f);
            const float var = q4 * (1.f / 128.f) - mean * mean;
            const float rs = rsqrtf(var + 1e-5f);
            int row = tbase + ((tt * RW + roww) << 4) + (lk << 2) + rr;
            if (row < M) {
                #pragma unroll
                for (int c = 0; c < 2; ++c)
                    Cf[(size_t)row * HH + col0 + (c << 4) + lr] =
                        (acc2[tt][c][rr] - mean) * rs * g2[c] + be2[c];
            }
        }
    }
}

// ---------------- fused K|V GEMM + score, CSR-ORDERED ----------------
template <int RT>
__global__ __launch_bounds__(512, 2) void kv_k(
    const unsigned short* __restrict__ hbf, const int* __restrict__ srcc,
    const unsigned short* __restrict__ ebfc,
    const unsigned short* __restrict__ Wt, const float* __restrict__ bias,
    const float* __restrict__ Q, const int* __restrict__ dstc,
    int M, unsigned short* __restrict__ V, float* __restrict__ sbuf)
{
    constexpr int ROWS = RT * 16;
    constexpr int Ktot = 256;
    constexpr int SI = ROWS / 32;
    __shared__ unsigned short Asl[2 * ROWS * 128];

    const int t = threadIdx.x;
    const int wid = t >> 6, lane = t & 63;
    const int lr = lane & 15, lk = lane >> 4;
    const int col0 = wid << 5;
    const int tbase = blockIdx.x * ROWS;

    int dstid[RT][4];
    if (wid < 4) {
        #pragma unroll
        for (int tt = 0; tt < RT; ++tt)
            #pragma unroll
            for (int rr = 0; rr < 4; ++rr) {
                int row = tbase + (tt << 4) + (lk << 2) + rr;
                dstid[tt][rr] = dstc[(row < M) ? row : M - 1];
            }
    }

    #pragma unroll
    for (int g = 0; g < 2; ++g) {
        const unsigned short* Ag = g ? ebfc : hbf;
        #pragma unroll
        for (int i = 0; i < SI; ++i) {
            int rl = ((i * 8 + wid) << 2) + (lane >> 4);
            int gr = tbase + rl; if (gr >= M) gr = M - 1;
            int rid = g ? gr : srcc[gr];     // e-chunk: contiguous CSR rows
            const unsigned short* srcp = Ag + (size_t)rid * HH + (((lane & 15) ^ (rl & 7)) << 3);
            unsigned short* dstp = &Asl[(g * ROWS + ((i * 8 + wid) << 2)) << 7];
            __builtin_amdgcn_global_load_lds((const __attribute__((address_space(1))) void*)srcp,
                                             (__attribute__((address_space(3))) void*)dstp, 16, 0, 0);
        }
    }

    f32x4 acc[RT][2];
    #pragma unroll
    for (int tt = 0; tt < RT; ++tt) { acc[tt][0] = (f32x4){0,0,0,0}; acc[tt][1] = (f32x4){0,0,0,0}; }

    __syncthreads();

    #pragma unroll
    for (int g = 0; g < 2; ++g) {
        bf16x8 b[4][2];
        #pragma unroll
        for (int s = 0; s < 4; ++s)
            #pragma unroll
            for (int c = 0; c < 2; ++c)
                b[s][c] = *(const bf16x8*)(Wt + (size_t)(col0 + (c << 4) + lr) * Ktot + (g << 7) + (s << 5) + (lk << 3));

        #pragma unroll
        for (int tt = 0; tt < RT; ++tt) {
            bf16x8 a[4];
            #pragma unroll
            for (int s = 0; s < 4; ++s) {
                const int c16 = ((s << 2) + lk) ^ (lr & 7);
                a[s] = *(const bf16x8*)&Asl[((g * ROWS + (tt << 4) + lr) << 7) + (c16 << 3)];
            }
            #pragma unroll
            for (int s = 0; s < 4; ++s) {
                acc[tt][0] = __builtin_amdgcn_mfma_f32_16x16x32_bf16(a[s], b[s][0], acc[tt][0], 0, 0, 0);
                acc[tt][1] = __builtin_amdgcn_mfma_f32_16x16x32_bf16(a[s], b[s][1], acc[tt][1], 0, 0, 0);
            }
        }
    }

    float bias2[2] = {bias[col0 + lr], bias[col0 + 16 + lr]};

    if (wid < 4) {
        #pragma unroll
        for (int tt = 0; tt < RT; ++tt) {
            #pragma unroll
            for (int rr = 0; rr < 4; ++rr) {
                int row = tbase + (tt << 4) + (lk << 2) + rr;
                int d = dstid[tt][rr];
                float q0 = Q[(size_t)d * HH + col0 + lr];
                float q1 = Q[(size_t)d * HH + col0 + 16 + lr];
                float p = (acc[tt][0][rr] + bias2[0]) * q0 + (acc[tt][1][rr] + bias2[1]) * q1;
                p += __shfl_xor(p, 1); p += __shfl_xor(p, 2);
                p += __shfl_xor(p, 4); p += __shfl_xor(p, 8);
                if (lr == 0 && row < M)
                    sbuf[(size_t)row * 4 + wid] = p * 0.17677669529663687f;
            }
        }
    } else {
        #pragma unroll
        for (int tt = 0; tt < RT; ++tt) {
            #pragma unroll
            for (int rr = 0; rr < 4; ++rr) {
                int row = tbase + (tt << 4) + (lk << 2) + rr;
                if (row >= M) continue;
                #pragma unroll
                for (int c = 0; c < 2; ++c)
                    V[(size_t)row * HH + (col0 - 128) + (c << 4) + lr] = f2bf(acc[tt][c][rr] + bias2[c]);
            }
        }
    }
}

// ---------------- per-node online-softmax aggregation (CSR-streaming, vectorized) ----------------
__global__ __launch_bounds__(256) void agg_k(const unsigned short* __restrict__ Vb,
                                             const float* __restrict__ s,
                                             const int* __restrict__ offsets,
                                             unsigned short* __restrict__ hagg)
{
    const int t = threadIdx.x;
    const int n = blockIdx.x * 4 + (t >> 6);
    if (n >= NN) return;
    const int lane = t & 63;
    const int c = lane << 1;
    const int h = lane >> 4;
    const int o0 = offsets[n], o1 = offsets[n + 1];
    float m = -1e30f, d = 0.f, a0 = 0.f, a1 = 0.f;
    for (int j = o0; j < o1; ++j) {
        const float sj = s[(size_t)j * 4 + h];
        ushort2 vv = *(const ushort2*)(Vb + (size_t)j * HH + c);
        float nm = fmaxf(m, sj);
        float sc = __expf(m - nm);
        float w  = __expf(sj - nm);
        d = d * sc + w;
        a0 = a0 * sc + w * bf2f(vv.x);
        a1 = a1 * sc + w * bf2f(vv.y);
        m = nm;
    }
    const bool any = (o1 > o0);
    ushort2 o;
    o.x = any ? f2bf(a0 / d) : 0;
    o.y = any ? f2bf(a1 / d) : 0;
    *(ushort2*)(hagg + (size_t)n * HH + c) = o;
}

extern "C" void kernel_launch(void* const* d_in, const int* in_sizes, int n_in,
                              void* d_out, int out_size, void* d_ws, size_t ws_size,
                              hipStream_t stream)
{
    const float* h   = (const float*)d_in[0];
    const float* e   = (const float*)d_in[1];
    const int*   src = (const int*)d_in[2];
    const int*   dst = (const int*)d_in[3];
    const float* Wq  = (const float*)d_in[4];
    const float* bq  = (const float*)d_in[5];
    const float* Wk  = (const float*)d_in[6];
    const float* bk  = (const float*)d_in[7];
    const float* Wv  = (const float*)d_in[8];
    const float* bv  = (const float*)d_in[9];
    const float* Wn1 = (const float*)d_in[10];
    const float* bn1 = (const float*)d_in[11];
    const float* Wn2 = (const float*)d_in[12];
    const float* bn2 = (const float*)d_in[13];
    const float* We1 = (const float*)d_in[14];
    const float* be1 = (const float*)d_in[15];
    const float* We2 = (const float*)d_in[16];
    const float* be2 = (const float*)d_in[17];
    const float* gh  = (const float*)d_in[18];
    const float* bh  = (const float*)d_in[19];
    const float* ge  = (const float*)d_in[20];
    const float* be_ = (const float*)d_in[21];
    (void)in_sizes; (void)n_in; (void)out_size; (void)ws_size;

    float* h_out = (float*)d_out;
    float* e_out = (float*)d_out + (size_t)NN * HH;

    char* ws = (char*)d_ws;
    size_t off = 0;
    auto carve = [&](size_t bytes) { void* p = ws + off; off += (bytes + 255) & ~(size_t)255; return p; };
    unsigned short* Vbuf = (unsigned short*)carve((size_t)EE * HH * 2);   // V bf16, CSR order
    unsigned short* ebfc = (unsigned short*)carve((size_t)EE * HH * 2);   // e bf16, CSR order
    float* Q      = (float*)carve((size_t)NN * HH * 4);
    float* sbuf   = (float*)carve((size_t)EE * 4 * 4);                    // scores, CSR order
    unsigned short* hagg = (unsigned short*)carve((size_t)NN * HH * 2);
    unsigned short* hobf = (unsigned short*)carve((size_t)NN * HH * 2);
    unsigned short* hbf  = (unsigned short*)carve((size_t)NN * HH * 2);
    int* cursor   = (int*)carve((size_t)NN * 4);
    int* offsets  = (int*)carve((size_t)(NN + 1) * 4);
    int* bsum     = (int*)carve(256 * 4);
    int* eids     = (int*)carve((size_t)EE * 4);
    int* srcc     = (int*)carve((size_t)EE * 4);
    int* dstc     = (int*)carve((size_t)EE * 4);
    unsigned short* Wq_s  = (unsigned short*)carve(128 * 128 * 2);
    unsigned short* Wkv_s = (unsigned short*)carve(256 * 256 * 2);
    unsigned short* Wn1_s = (unsigned short*)carve(128 * 128 * 2);
    unsigned short* Wn2_s = (unsigned short*)carve(128 * 128 * 2);
    unsigned short* We1_s = (unsigned short*)carve(128 * 384 * 2);
    unsigned short* We2_s = (unsigned short*)carve(128 * 128 * 2);
    float* b_kv   = (float*)carve(256 * 4);

    const int nb = (NN + 255) / 256;

    // weight prep (bf16 transpose) + combined KV bias
    wprep_k<<<(128 * 128 + 255) / 256, 256, 0, stream>>>(Wq,  Wq_s,  128, 128, 0, 128);
    wprep_k<<<(256 * 128 + 255) / 256, 256, 0, stream>>>(Wk,  Wkv_s, 256, 128, 0, 256);
    wprep_k<<<(256 * 128 + 255) / 256, 256, 0, stream>>>(Wv,  Wkv_s, 256, 128, 128, 256);
    wprep_k<<<(128 * 128 + 255) / 256, 256, 0, stream>>>(Wn1, Wn1_s, 128, 128, 0, 128);
    wprep_k<<<(128 * 128 + 255) / 256, 256, 0, stream>>>(Wn2, Wn2_s, 128, 128, 0, 128);
    wprep_k<<<(384 * 128 + 255) / 256, 256, 0, stream>>>(We1, We1_s, 384, 128, 0, 384);
    wprep_k<<<(128 * 128 + 255) / 256, 256, 0, stream>>>(We2, We2_s, 128, 128, 0, 128);
    hipMemcpyAsync(b_kv,       bk, 128 * 4, hipMemcpyDeviceToDevice, stream);
    hipMemcpyAsync(b_kv + 128, bv, 128 * 4, hipMemcpyDeviceToDevice, stream);

    // h -> bf16
    cvt_k<<<(NN * HH / 8 + 255) / 256, 256, 0, stream>>>(h, hbf, (long)NN * HH / 8);

    // CSR build (+ CSR-ordered src/dst)
    hipMemsetAsync(cursor, 0, (size_t)NN * 4, stream);
    hist_k<<<(EE + 255) / 256, 256, 0, stream>>>(dst, cursor);
    blocksum_k<<<nb, 256, 0, stream>>>(cursor, bsum);
    scanb_k<<<1, 256, 0, stream>>>(bsum, nb);
    offsets_k<<<nb, 256, 0, stream>>>(cursor, bsum, offsets, cursor);
    fill_k<<<(EE + 255) / 256, 256, 0, stream>>>(src, dst, cursor, eids, srcc, dstc);

    // e -> bf16 in CSR order (kv's e-stage becomes contiguous)
    cvtcsr_k<<<(EE * 16 + 255) / 256, 256, 0, stream>>>(e, eids, ebfc);

    // Q = h @ Wq + bq  (f32 out)
    mm4_k<1, 4, 4, 0><<<(NN + 127) / 128, 512, 0, stream>>>(
        hbf, nullptr, Wq_s, bq, NN, Q, nullptr, 128);

    // fused K|V GEMM + score in CSR order
    kv_k<4><<<EE / 64, 512, 0, stream>>>(
        hbf, srcc, ebfc, Wkv_s, b_kv, Q, dstc, EE, Vbuf, sbuf);

    agg_k<<<(NN + 3) / 4, 256, 0, stream>>>(Vbuf, sbuf, offsets, hagg);

    // fused node MLP (emits h_out f32 + hobf bf16)
    mlp_k<1, 4><<<(NN + 127) / 128, 512, 0, stream>>>(
        hagg, nullptr, Wn1_s, bn1, Wn2_s, bn2, NN, h_out, hobf, h, gh, bh);

    // fused edge MLP: e staged once as f32 (GEMM input + residual)
    mlpe_k<<<EE / 64, 512, 0, stream>>>(
        hobf, src, dst, e, We1_s, be1, We2_s, be2, EE, e_out, ge, be_);
}